// Round 9
// baseline (851.550 us; speedup 1.0000x reference)
//
#include <hip/hip_runtime.h>
#include <cstdint>

// Problem constants
constexpr int Cc = 95;    // input channels
constexpr int Hh = 128;   // hidden
constexpr int G  = 512;   // 4*H gates
constexpr int Bb = 256;   // batch
constexpr int Tt = 1000;  // timesteps
constexpr int TC = 125;   // chunk length
constexpr int NCH = 8;    // chunks
#define EPSBN 1e-5f

typedef _Float16 half8  __attribute__((ext_vector_type(8)));
typedef float floatx4 __attribute__((ext_vector_type(4)));
typedef float float4u __attribute__((ext_vector_type(4), aligned(4)));

__device__ __forceinline__ unsigned pku(float a, float b) {
  return __builtin_bit_cast(unsigned, __builtin_amdgcn_cvt_pkrtz(a, b));
}
__device__ __forceinline__ floatx4 mfma16(uint4 a, uint4 b, floatx4 c) {
  return __builtin_amdgcn_mfma_f32_16x16x32_f16(
      __builtin_bit_cast(half8, a), __builtin_bit_cast(half8, b), c, 0, 0, 0);
}
// sigmoid: inf-safe without clamps (exp->inf => rcp->0; exp->0 => 1)
__device__ __forceinline__ float fsigm(float y) {
  float e = __expf(-y);
  return __fdividef(1.f, 1.f + e);
}
// tanh via exp(2x); upper clamp only (e->0 gives -1 correctly)
__device__ __forceinline__ float ftanh2(float x) {
  float yy = fminf(60.f, 2.f * x);
  float e = __expf(yy);
  return __fdividef(e - 1.f, e + 1.f);
}

// ---------------------------------------------------------------------------
// K0a: fold BN into W_ih -> Wp f16 [512][96] (k padded), bias' per gate row.
// ---------------------------------------------------------------------------
__global__ __launch_bounds__(512)
void k0_prep(const float* __restrict__ gamma, const float* __restrict__ beta,
             const float* __restrict__ rmean, const float* __restrict__ rvar,
             const float* __restrict__ W_ih, const float* __restrict__ b_ih,
             const float* __restrict__ b_hh, float* __restrict__ biasp,
             _Float16* __restrict__ Wp) {
  __shared__ float scl[Cc], sft[Cc];
  const int t = threadIdx.x;
  if (t < Cc) {
    float s = gamma[t] * rsqrtf(rvar[t] + EPSBN);
    scl[t] = s;
    sft[t] = beta[t] - rmean[t] * s;
  }
  __syncthreads();
  float acc = b_ih[t] + b_hh[t];
  const float* wr = W_ih + (size_t)t * Cc;
  for (int c = 0; c < Cc; ++c) {
    float w = wr[c];
    acc = fmaf(sft[c], w, acc);
    Wp[t * 96 + c] = (_Float16)(w * scl[c]);
  }
  Wp[t * 96 + 95] = (_Float16)0.f;
  biasp[t] = acc;
}

// ---------------------------------------------------------------------------
// K0b: x (f32, row len 95) -> xh (f16, row len 96, zero-padded).
// ---------------------------------------------------------------------------
__global__ __launch_bounds__(256)
void k0_xh(const float* __restrict__ x, _Float16* __restrict__ xh) {
  const size_t N = (size_t)Bb * Tt * 96;
  for (size_t i = (size_t)blockIdx.x * 256 + threadIdx.x; i < N;
       i += (size_t)gridDim.x * 256) {
    size_t row = i / 96;
    int c = (int)(i - row * 96);
    float v = (c < Cc) ? x[row * Cc + c] : 0.f;
    xh[i] = (_Float16)v;
  }
}

// ---------------------------------------------------------------------------
// K2 mega-kernel: 256 blocks (1 batch each) x 512 thr (8 waves, 2/SIMD).
// Wave w8 owns units [16*w8, 16*w8+16): afr = W_hh rows f16, 64 VGPR.
// Per step: ring consume+reload (1 dwordx4) -> 4x ds_read_b128 h -> 16 MFMA
// (kc-outer) -> interleaved next-chunk GEMM pair (3 MFMA + 4 stores) ->
// 12-cndmask gate extraction -> activations -> h f16 -> LDS; raw s_barrier
// with lgkmcnt-only wait. Next chunk's xw GEMM (own batch, xh . Wp^T)
// fills the latency stalls; whole T=1000 in ONE launch (h,c in regs).
// ---------------------------------------------------------------------------
__global__ __attribute__((amdgpu_flat_work_group_size(512, 512)))
__attribute__((amdgpu_waves_per_eu(2, 2)))
void k2_mega(const _Float16* __restrict__ xh, const _Float16* __restrict__ Wp,
             const float* __restrict__ biasp, const float* __restrict__ W_hh,
             const float* __restrict__ fc_w, const float* __restrict__ fc_b,
             float* __restrict__ out, float* __restrict__ xw0,
             float* __restrict__ xw1) {
  __shared__ __align__(16) _Float16 h2[2][Hh];
  __shared__ float h32[Hh];

  const int b = blockIdx.x;
  const int tid = threadIdx.x;
  const int w8 = tid >> 6, lane = tid & 63;
  const int l15 = lane & 15, lg = lane >> 4;
  const int rr = l15 & 3;
  const int u = 16 * w8 + 4 * lg + rr;  // unit this lane updates
  const bool owner = (l15 < 4);

  // Recurrence A-frags: 4 tiles (gate q) x 4 kc, rows q*128 + 16*w8 + l15
  uint4 afr[4][4];
#pragma unroll
  for (int q = 0; q < 4; ++q) {
    const float* wr = W_hh + (size_t)(q * 128 + 16 * w8 + l15) * Hh + 8 * lg;
#pragma unroll
    for (int kc = 0; kc < 4; ++kc) {
      float4u p0 = *reinterpret_cast<const float4u*>(wr + 32 * kc);
      float4u p1 = *reinterpret_cast<const float4u*>(wr + 32 * kc + 4);
      afr[q][kc] = make_uint4(pku(p0[0], p0[1]), pku(p0[2], p0[3]),
                              pku(p1[0], p1[1]), pku(p1[2], p1[3]));
    }
  }

  // GEMM setup: this wave covers gate cols n in [64*w8, 64*w8+64)
  const int qcol = w8 >> 1;  // n>>7 for this wave's cols
  float biasg[4];
#pragma unroll
  for (int ct = 0; ct < 4; ++ct) biasg[ct] = biasp[64 * w8 + 16 * ct + l15];

  uint4 Ac[3], Bp[3];  // GEMM A (per rowtile) and B (per pair) fragments

#define G_ISSUE_A(RT, TB)                                                      \
  {                                                                            \
    const _Float16* xa =                                                       \
        xh + ((size_t)b * Tt + (TB) + 16 * (RT) + l15) * 96 + 8 * lg;          \
    Ac[0] = *reinterpret_cast<const uint4*>(xa);                               \
    Ac[1] = *reinterpret_cast<const uint4*>(xa + 32);                          \
    Ac[2] = *reinterpret_cast<const uint4*>(xa + 64);                          \
  }
#define G_ISSUE_B(CT)                                                          \
  {                                                                            \
    const _Float16* wb =                                                       \
        Wp + (size_t)(64 * w8 + 16 * (CT) + l15) * 96 + 8 * lg;                \
    Bp[0] = *reinterpret_cast<const uint4*>(wb);                               \
    Bp[1] = *reinterpret_cast<const uint4*>(wb + 32);                          \
    Bp[2] = *reinterpret_cast<const uint4*>(wb + 64);                          \
  }
#define G_EXEC(RT, CT, BUFN)                                                   \
  {                                                                            \
    floatx4 ag = {0.f, 0.f, 0.f, 0.f};                                         \
    ag = mfma16(Ac[0], Bp[0], ag);                                             \
    ag = mfma16(Ac[1], Bp[1], ag);                                             \
    ag = mfma16(Ac[2], Bp[2], ag);                                             \
    int ucol = (64 * w8 + 16 * (CT) + l15) & 127;                              \
    float bs = biasg[CT];                                                      \
    _Pragma("unroll") for (int r_ = 0; r_ < 4; ++r_) {                         \
      int m_ = 16 * (RT) + 4 * lg + r_;                                        \
      if (m_ < TC)                                                             \
        (BUFN)[((size_t)b * TC + m_) * G + ucol * 4 + qcol] = ag[r_] + bs;     \
    }                                                                          \
  }

  // Prologue: GEMM chunk 0 -> xw0 (own batch only; ~trivial per block)
  for (int rt = 0; rt < 8; ++rt) {
    G_ISSUE_A(rt, 0)
#pragma unroll
    for (int ct = 0; ct < 4; ++ct) {
      G_ISSUE_B(ct)
      G_EXEC(rt, ct, xw0)
    }
  }
  asm volatile("s_waitcnt vmcnt(0)" ::: "memory");
  __syncthreads();

  float creg = 0.f, hreg = 0.f;
  if (owner) h2[0][u] = (_Float16)0.f;
  __syncthreads();

  const float* bc = xw0;  // consume buffer
  float* bn = xw1;        // produce buffer

  for (int c = 0; c < NCH; ++c) {
    const bool dog = (c < NCH - 1);  // do GEMM for next chunk
    const int tnext = (c + 1) * TC;
    const float* xrb = bc + (size_t)b * TC * G + 4 * u;

    // ring refill (4 deep)
    float4u rg[4];
#pragma unroll
    for (int i = 0; i < 4; ++i)
      rg[i] = *reinterpret_cast<const float4u*>(xrb + (size_t)i * G);

#define K2_STEP(TL, SL)                                                        \
  {                                                                            \
    const int tl_ = (TL);                                                      \
    const int rb_ = tl_ & 1;                                                   \
    float4u cg4 = rg[SL];                                                      \
    if (tl_ + 4 < TC)                                                          \
      rg[SL] = *reinterpret_cast<const float4u*>(xrb + (size_t)(tl_ + 4) * G); \
    const int p_ = tl_ >> 2;                                                   \
    if (dog && (tl_ & 3) == 0) {                                               \
      if ((p_ & 3) == 0) G_ISSUE_A(p_ >> 2, tnext)                             \
      G_ISSUE_B(p_ & 3)                                                        \
    }                                                                          \
    uint4 bfr[4];                                                              \
    _Pragma("unroll") for (int kc = 0; kc < 4; ++kc)                           \
        bfr[kc] = *reinterpret_cast<const uint4*>(&h2[rb_][32 * kc + 8 * lg]); \
    floatx4 acc[4] = {};                                                       \
    _Pragma("unroll") for (int kc = 0; kc < 4; ++kc)                           \
        _Pragma("unroll") for (int q_ = 0; q_ < 4; ++q_)                       \
            acc[q_] = mfma16(afr[q_][kc], bfr[kc], acc[q_]);                   \
    if (dog && (tl_ & 3) == 1) G_EXEC(p_ >> 2, p_ & 3, bn)                     \
    float gq[4];                                                               \
    _Pragma("unroll") for (int q_ = 0; q_ < 4; ++q_) {                         \
      float lo = (rr & 1) ? acc[q_][1] : acc[q_][0];                           \
      float hi = (rr & 1) ? acc[q_][3] : acc[q_][2];                           \
      gq[q_] = (rr & 2) ? hi : lo;                                             \
    }                                                                          \
    float i_ = fsigm(gq[0] + cg4[0]);                                          \
    float f_ = fsigm(gq[1] + cg4[1]);                                          \
    float g_ = ftanh2(gq[2] + cg4[2]);                                         \
    float o_ = fsigm(gq[3] + cg4[3]);                                          \
    creg = fmaf(f_, creg, i_ * g_);                                            \
    hreg = o_ * ftanh2(creg);                                                  \
    if (owner) h2[rb_ ^ 1][u] = (_Float16)hreg;                                \
    asm volatile("s_waitcnt lgkmcnt(0)" ::: "memory");                         \
    __builtin_amdgcn_s_barrier();                                              \
    __builtin_amdgcn_sched_barrier(0);                                         \
  }

    int tl = 0;
    for (; tl + 4 <= TC; tl += 4) {
      K2_STEP(tl + 0, 0)
      K2_STEP(tl + 1, 1)
      K2_STEP(tl + 2, 2)
      K2_STEP(tl + 3, 3)
    }
    K2_STEP(124, 0)  // TC = 125 = 31*4 + 1
#undef K2_STEP

    if (dog) {
      G_EXEC(7, 3, bn)  // pair 31 (issued at tl=124), finish next chunk
      asm volatile("s_waitcnt vmcnt(0)" ::: "memory");
    }
    __syncthreads();
    const float* tmp = bc;
    bc = bn;
    bn = const_cast<float*>(tmp);
  }

  if (owner) h32[u] = hreg;
  __syncthreads();

  if (tid < 4) {
    float s = fc_b[tid];
    for (int jj = 0; jj < Hh; ++jj) s = fmaf(h32[jj], fc_w[tid * Hh + jj], s);
    out[b * 4 + tid] = s;
  }
#undef G_ISSUE_A
#undef G_ISSUE_B
#undef G_EXEC
}

// ---------------------------------------------------------------------------
extern "C" void kernel_launch(void* const* d_in, const int* in_sizes, int n_in,
                              void* d_out, int out_size, void* d_ws,
                              size_t ws_size, hipStream_t stream) {
  const float* x     = (const float*)d_in[0];
  const float* gamma = (const float*)d_in[1];
  const float* beta  = (const float*)d_in[2];
  const float* rmean = (const float*)d_in[3];
  const float* rvar  = (const float*)d_in[4];
  const float* W_ih  = (const float*)d_in[5];
  const float* W_hh  = (const float*)d_in[6];
  const float* b_ih  = (const float*)d_in[7];
  const float* b_hh  = (const float*)d_in[8];
  const float* fc_w  = (const float*)d_in[9];
  const float* fc_b  = (const float*)d_in[10];
  float* out = (float*)d_out;

  // ws layout (≈180.3 MB; ws proven ≥262 MB in earlier rounds)
  char* ws = reinterpret_cast<char*>(d_ws);
  const size_t S1 = (size_t)Bb * TC * G * 4;  // 65.5 MB per xw buffer
  float* xw0 = reinterpret_cast<float*>(ws);
  float* xw1 = reinterpret_cast<float*>(ws + S1);
  float* bia = reinterpret_cast<float*>(ws + 2 * S1);
  _Float16* Wp = reinterpret_cast<_Float16*>(ws + 2 * S1 + 2048);
  _Float16* xh = reinterpret_cast<_Float16*>(ws + 2 * S1 + 2048 + 98304);

  k0_prep<<<dim3(1), dim3(512), 0, stream>>>(gamma, beta, rmean, rvar, W_ih,
                                             b_ih, b_hh, bia, Wp);
  k0_xh<<<dim3(2048), dim3(256), 0, stream>>>(x, xh);
  k2_mega<<<dim3(Bb), dim3(512), 0, stream>>>(xh, Wp, bia, W_hh, fc_w, fc_b,
                                              out, xw0, xw1);
}